// Round 6
// baseline (409.025 us; speedup 1.0000x reference)
//
#include <hip/hip_runtime.h>

// RNN: B=256, T=512, I=256, H=128, O=1000, fp32 in/out. Internals fp16.
// ws: xp[131072][128] fp32 = 64 MiB. h_last[r] overwrites xp[r*512+0][:].
// k_rnn5 computes the TRANSPOSED step GEMM D[j][m] = W_hh (A) x h^T (B):
//   - B-frag reads: h[m][k] row-major, 16B/lane ds_read_b128, 4 waves only
//   - D rows are j -> thread's 4 values = 4 consecutive j at fixed m -> ds_write_b64
//   LDS pipe per CU-step: 16 b128 reads + 8 b64 writes (~256 cyc) vs 576 before.

#define HID    128
#define TSTEPS 512
#define BATCH  256
#define INDIM  256
#define ODIM   1000

typedef _Float16 f16x8 __attribute__((ext_vector_type(8)));
typedef __fp16   fp16x2 __attribute__((ext_vector_type(2)));
typedef float    f32x4 __attribute__((ext_vector_type(4)));

__device__ __forceinline__ unsigned pk16(float a, float b) {
    union { fp16x2 h; unsigned u; } t;
    t.h = __builtin_amdgcn_cvt_pkrtz(a, b);   // 2 fp32 -> packed 2 fp16 (RTZ)
    return t.u;
}
// tanh: exp2 overflow->inf->rcp->0 gives +1; underflow gives -1 exactly.
__device__ __forceinline__ float tanh_fast(float v) {
    float e = __expf(2.f * v);
    float r = __builtin_amdgcn_rcpf(e + 1.f);
    return __builtin_fmaf(-2.f, r, 1.f);
}

// ---------------- Kernel 1: xp = x @ W_ih^T + (b_ih + b_hh) ----------------
// MFMA 16x16x32 f16, double-buffered LDS staging, fp16 conversion at stage time.
// (unchanged from round 5 — passing; awaiting its own profile data)
__global__ __launch_bounds__(256) void k_phase1(const float* __restrict__ x,
                                                const float* __restrict__ Wih,
                                                const float* __restrict__ bih,
                                                const float* __restrict__ bhh,
                                                float* __restrict__ xp) {
    __shared__ __align__(16) _Float16 xs[2][4096];
    __shared__ __align__(16) _Float16 wsm[2][4096];

    const int tid  = threadIdx.x;
    const int wave = tid >> 6, lane = tid & 63;
    const int quad = lane >> 4, l16 = lane & 15;
    const int wm = wave >> 1, wn = wave & 1;
    const int m0 = blockIdx.x * 128;

    int srow[4], scol[4], sdst[4];
#pragma unroll
    for (int q = 0; q < 4; q++) {
        int li = q * 256 + tid;
        srow[q] = li >> 3;
        scol[q] = li & 7;
        sdst[q] = srow[q] * 32 + ((((scol[q] >> 1) ^ srow[q]) & 3) << 3) + ((scol[q] & 1) << 2);
    }

    float bias_v[4];
#pragma unroll
    for (int nt = 0; nt < 4; nt++) {
        int j = wn * 64 + nt * 16 + l16;
        bias_v[nt] = bih[j] + bhh[j];
    }

    float4 rx[4], rw[4];
#define LOAD_STAGE(KC)                                                              \
    {                                                                               \
        _Pragma("unroll") for (int q = 0; q < 4; q++) {                             \
            rx[q] = *(const float4*)(x + (size_t)(m0 + srow[q]) * INDIM + (KC) * 32 + scol[q] * 4); \
            rw[q] = *(const float4*)(Wih + (size_t)srow[q] * INDIM + (KC) * 32 + scol[q] * 4);      \
        }                                                                           \
    }
#define WRITE_STAGE(BUF)                                                            \
    {                                                                               \
        _Pragma("unroll") for (int q = 0; q < 4; q++) {                             \
            uint2 px, pw;                                                           \
            px.x = pk16(rx[q].x, rx[q].y); px.y = pk16(rx[q].z, rx[q].w);           \
            pw.x = pk16(rw[q].x, rw[q].y); pw.y = pk16(rw[q].z, rw[q].w);           \
            *(uint2*)&xs[BUF][sdst[q]]  = px;                                       \
            *(uint2*)&wsm[BUF][sdst[q]] = pw;                                       \
        }                                                                           \
    }

    f32x4 acc[4][4];
#pragma unroll
    for (int mt = 0; mt < 4; mt++)
#pragma unroll
        for (int nt = 0; nt < 4; nt++) {
            acc[mt][nt].x = 0.f; acc[mt][nt].y = 0.f;
            acc[mt][nt].z = 0.f; acc[mt][nt].w = 0.f;
        }

    LOAD_STAGE(0);
    WRITE_STAGE(0);
    __syncthreads();

    for (int kc = 0; kc < 8; kc++) {
        const int b = kc & 1;
        if (kc < 7) LOAD_STAGE(kc + 1);

        f16x8 a[4], bw[4];
#pragma unroll
        for (int mt = 0; mt < 4; mt++) {
            int row = wm * 64 + mt * 16 + l16;
            a[mt] = *(const f16x8*)&xs[b][row * 32 + (((quad ^ row) & 3) << 3)];
        }
#pragma unroll
        for (int nt = 0; nt < 4; nt++) {
            int row = wn * 64 + nt * 16 + l16;
            bw[nt] = *(const f16x8*)&wsm[b][row * 32 + (((quad ^ row) & 3) << 3)];
        }
#pragma unroll
        for (int mt = 0; mt < 4; mt++)
#pragma unroll
            for (int nt = 0; nt < 4; nt++)
                acc[mt][nt] = __builtin_amdgcn_mfma_f32_16x16x32_f16(a[mt], bw[nt], acc[mt][nt], 0, 0, 0);

        if (kc < 7) WRITE_STAGE(b ^ 1);
        __syncthreads();
    }

#pragma unroll
    for (int mt = 0; mt < 4; mt++)
#pragma unroll
        for (int nt = 0; nt < 4; nt++)
#pragma unroll
            for (int reg = 0; reg < 4; reg++) {
                int row = m0 + wm * 64 + mt * 16 + quad * 4 + reg;
                xp[(size_t)row * HID + wn * 64 + nt * 16 + l16] = acc[mt][nt][reg] + bias_v[nt];
            }
#undef LOAD_STAGE
#undef WRITE_STAGE
}

// ---------------- Kernel 2: recurrence, transposed GEMM ---------------------
// 16 blocks x 256 thr (4 waves). Block: batch rows [16b,16b+16). Wave w: j in
// [32w,32w+32). A = W_hh (j x k) in VGPRs; B = h^T from LDS (h row-major);
// D[j][m]: row=j=quad*4+reg, col=m=l16. h rows 128 fp16 = 16 chunks of 16B,
// XOR-swizzled chunk c -> c ^ m. One ds_write_b64 per (thread, jt).
#define RNN_STEP5(TV, XQI, XQC, PB) {                                             \
    {                                                                             \
        float h0 = tanh_fast(C[0][0]), h1 = tanh_fast(C[0][1]);                   \
        float h2 = tanh_fast(C[0][2]), h3 = tanh_fast(C[0][3]);                   \
        uint2 pw; pw.x = pk16(h0, h1); pw.y = pk16(h2, h3);                       \
        *(uint2*)&hp[PB][wadr0] = pw;                                             \
        h0 = tanh_fast(C[1][0]); h1 = tanh_fast(C[1][1]);                         \
        h2 = tanh_fast(C[1][2]); h3 = tanh_fast(C[1][3]);                         \
        pw.x = pk16(h0, h1); pw.y = pk16(h2, h3);                                 \
        *(uint2*)&hp[PB][wadr1] = pw;                                             \
    }                                                                             \
    if ((TV) + 4 < TSTEPS) {                                                      \
        XQI[0] = *(const float4*)(xb + ((TV) + 4) * HID);                         \
        XQI[1] = *(const float4*)(xb + ((TV) + 4) * HID + 16);                    \
    }                                                                             \
    __syncthreads();                                                              \
    f16x8 Bv[4];                                                                  \
    _Pragma("unroll") for (int kc = 0; kc < 4; kc++)                              \
        Bv[kc] = *(const f16x8*)&hp[PB][radr[kc]];                                \
    _Pragma("unroll") for (int jt = 0; jt < 2; jt++) {                            \
        f32x4 c;                                                                  \
        c.x = XQC[jt].x; c.y = XQC[jt].y; c.z = XQC[jt].z; c.w = XQC[jt].w;       \
        c = __builtin_amdgcn_mfma_f32_16x16x32_f16(Af[jt][0], Bv[0], c, 0, 0, 0); \
        c = __builtin_amdgcn_mfma_f32_16x16x32_f16(Af[jt][1], Bv[1], c, 0, 0, 0); \
        c = __builtin_amdgcn_mfma_f32_16x16x32_f16(Af[jt][2], Bv[2], c, 0, 0, 0); \
        c = __builtin_amdgcn_mfma_f32_16x16x32_f16(Af[jt][3], Bv[3], c, 0, 0, 0); \
        C[jt] = c;                                                                \
    }                                                                             \
}

__global__ __launch_bounds__(256) void k_rnn5(const float* __restrict__ Whh,
                                              float* __restrict__ ws) {
    __shared__ __align__(16) _Float16 hp[2][16 * 128];
    const int tid  = threadIdx.x;
    const int wave = tid >> 6, lane = tid & 63;
    const int quad = lane >> 4, l16 = lane & 15;
    const int r0   = blockIdx.x * 16;
    const int jb0  = wave * 32;          // wave's j range: [jb0, jb0+32)

    // A-frags: W_hh[j][k], j = jb0 + jt*16 + l16 (A's m-index), k = kc*32 + quad*8 + i
    f16x8 Af[2][4];
#pragma unroll
    for (int jt = 0; jt < 2; jt++)
#pragma unroll
        for (int kc = 0; kc < 4; kc++) {
            const float* p = Whh + (size_t)(jb0 + jt * 16 + l16) * HID + kc * 32 + quad * 8;
            float4 e0 = *(const float4*)p, e1 = *(const float4*)(p + 4);
            union { unsigned u[4]; f16x8 v; } t;
            t.u[0] = pk16(e0.x, e0.y); t.u[1] = pk16(e0.z, e0.w);
            t.u[2] = pk16(e1.x, e1.y); t.u[3] = pk16(e1.z, e1.w);
            Af[jt][kc] = t.v;
        }

    // LDS addresses (fp16 units). Write: h[m=l16][j..j+3] packed b64.
    const int jg0 = jb0 + quad * 4;          // jt=0 j-group
    const int jg1 = jb0 + 16 + quad * 4;     // jt=1
    const int wadr0 = l16 * 128 + ((((jg0 >> 3) ^ l16) & 15) << 3) + (jg0 & 7);
    const int wadr1 = l16 * 128 + ((((jg1 >> 3) ^ l16) & 15) << 3) + (jg1 & 7);
    // Read: B[k][n=m]: m = l16, k-chunk (kc*4+quad), b128
    int radr[4];
#pragma unroll
    for (int kc = 0; kc < 4; kc++)
        radr[kc] = l16 * 128 + ((((kc * 4 + quad) ^ l16) & 15) << 3);

    // xq: thread (jt) needs xp[(r0+l16)*512 + t][jb0 + jt*16 + quad*4 .. +3]
    const float* xb = ws + (size_t)(r0 + l16) * (TSTEPS * HID) + jb0 + quad * 4;

    // C init = xq_0 (h_{-1}=0); prefetch xq_1..3
    f32x4 C[2];
    float4 Q0[2], Q1[2], Q2[2], Q3[2];
    {
        float4 a = *(const float4*)(xb);
        float4 b = *(const float4*)(xb + 16);
        C[0].x = a.x; C[0].y = a.y; C[0].z = a.z; C[0].w = a.w;
        C[1].x = b.x; C[1].y = b.y; C[1].z = b.z; C[1].w = b.w;
    }
    Q1[0] = *(const float4*)(xb + 1 * HID); Q1[1] = *(const float4*)(xb + 1 * HID + 16);
    Q2[0] = *(const float4*)(xb + 2 * HID); Q2[1] = *(const float4*)(xb + 2 * HID + 16);
    Q3[0] = *(const float4*)(xb + 3 * HID); Q3[1] = *(const float4*)(xb + 3 * HID + 16);

    for (int t = 0; t < 508; t += 4) {
        RNN_STEP5(t,     Q0, Q1, 0);
        RNN_STEP5(t + 1, Q1, Q2, 1);
        RNN_STEP5(t + 2, Q2, Q3, 0);
        RNN_STEP5(t + 3, Q3, Q0, 1);
    }
    RNN_STEP5(508, Q0, Q1, 0);
    RNN_STEP5(509, Q1, Q2, 1);
    RNN_STEP5(510, Q2, Q3, 0);

    // C = pre-activation of t=511. h_511 -> fp32 over xp[r][0][:] (own rows).
#pragma unroll
    for (int jt = 0; jt < 2; jt++)
#pragma unroll
        for (int reg = 0; reg < 4; reg++)
            ws[(size_t)(r0 + l16) * (TSTEPS * HID) + jb0 + jt * 16 + quad * 4 + reg] =
                tanh_fast(C[jt][reg]);
}

// ---------------- Kernel 3: out = h_last @ W_fc^T + b_fc --------------------
__global__ __launch_bounds__(256) void k_fc(const float* __restrict__ ws,
                                            const float* __restrict__ Wfc,
                                            const float* __restrict__ bfc,
                                            float* __restrict__ out) {
    __shared__ float hb[HID];
    const int b   = blockIdx.x;
    const int tid = threadIdx.x;
    if (tid < HID) hb[tid] = ws[(size_t)b * (TSTEPS * HID) + tid];
    __syncthreads();

    for (int o = tid; o < ODIM; o += 256) {
        const float* wr = Wfc + (size_t)o * HID;
        float acc = 0.f;
#pragma unroll
        for (int q = 0; q < 32; q++) {
            float4 wv = *(const float4*)(wr + q * 4);
            float4 hv = *(const float4*)&hb[q * 4];
            acc += wv.x * hv.x + wv.y * hv.y + wv.z * hv.z + wv.w * hv.w;
        }
        out[(size_t)b * ODIM + o] = acc + bfc[o];
    }
}

extern "C" void kernel_launch(void* const* d_in, const int* in_sizes, int n_in,
                              void* d_out, int out_size, void* d_ws, size_t ws_size,
                              hipStream_t stream) {
    const float* x   = (const float*)d_in[0];
    const float* Wih = (const float*)d_in[1];
    const float* Whh = (const float*)d_in[2];
    const float* bih = (const float*)d_in[3];
    const float* bhh = (const float*)d_in[4];
    const float* Wfc = (const float*)d_in[5];
    const float* bfc = (const float*)d_in[6];
    float* out = (float*)d_out;
    float* ws  = (float*)d_ws;  // 64 MiB xp

    k_phase1<<<dim3(1024), dim3(256), 0, stream>>>(x, Wih, bih, bhh, ws);
    k_rnn5  <<<dim3(16),   dim3(256), 0, stream>>>(Whh, ws);
    k_fc    <<<dim3(BATCH), dim3(256), 0, stream>>>(ws, Wfc, bfc, out);
}